// Round 1
// baseline (469.554 us; speedup 1.0000x reference)
//
#include <hip/hip_runtime.h>

#define NN 10000
#define NE 160000
#define KD 1433

// ---------- edge dtype detect + repack (int64 vs int32 robustness) ----------
__global__ __launch_bounds__(256) void detect_kernel(const int* __restrict__ e, int* __restrict__ flag) {
    __shared__ int nz;
    if (threadIdx.x == 0) nz = 0;
    __syncthreads();
    int cnt = 0;
    for (int i = threadIdx.x; i < 4000; i += 256)
        if (e[2 * i + 1] != 0) cnt++;
    if (cnt) atomicAdd(&nz, cnt);
    __syncthreads();
    if (threadIdx.x == 0) *flag = (nz == 0) ? 1 : 0;  // 1 => data is int64
}

__global__ __launch_bounds__(256) void repack_kernel(const int* __restrict__ e, const int* __restrict__ flag,
                                                     int* __restrict__ srcI, int* __restrict__ dstI) {
    int i = blockIdx.x * 256 + threadIdx.x;
    if (i >= NE) return;
    if (*flag) {  // int64 little-endian: take low words
        srcI[i] = e[2 * i];
        dstI[i] = e[2 * (NE + i)];
    } else {
        srcI[i] = e[i];
        dstI[i] = e[NE + i];
    }
}

// ---------- degree ----------
__global__ __launch_bounds__(256) void deg_kernel(const int* __restrict__ dst, float* __restrict__ deg) {
    int i = blockIdx.x * 256 + threadIdx.x;
    if (i < NE) atomicAdd(&deg[dst[i]], 1.0f);
}

__global__ __launch_bounds__(256) void deginv_kernel(float* __restrict__ deg) {
    int i = blockIdx.x * 256 + threadIdx.x;
    if (i < NN) deg[i] = (deg[i] > 0.f) ? (1.0f / deg[i]) : 0.f;
}

// ---------- layer-1 GEMM: y[n][0:64]=x@W1l.T, y[n][64:128]=x@W1r.T ----------
__global__ __launch_bounds__(256) void mm1_kernel(const float* __restrict__ x, const float* __restrict__ Wl,
                                                  const float* __restrict__ Wr, float* __restrict__ y) {
    __shared__ float Xs[32][17];
    __shared__ float Ws[128][17];
    const int t = threadIdx.x;
    const int n0 = blockIdx.x * 32;
    const int tr = t >> 5;  // 0..7  -> rows tr*4..tr*4+3
    const int tc = t & 31;  // 0..31 -> cols tc*4..tc*4+3
    float acc[4][4] = {};
    for (int k0 = 0; k0 < KD; k0 += 16) {
        #pragma unroll
        for (int i = 0; i < 2; ++i) {  // Xs: 32x16
            int e = t + i * 256;
            int row = e >> 4, col = e & 15;
            int n = n0 + row, k = k0 + col;
            Xs[row][col] = (n < NN && k < KD) ? x[n * KD + k] : 0.f;
        }
        #pragma unroll
        for (int i = 0; i < 8; ++i) {  // Ws: 128x16
            int e = t + i * 256;
            int row = e >> 4, col = e & 15;
            int k = k0 + col;
            float v = 0.f;
            if (k < KD) v = (row < 64) ? Wl[row * KD + k] : Wr[(row - 64) * KD + k];
            Ws[row][col] = v;
        }
        __syncthreads();
        #pragma unroll
        for (int kk = 0; kk < 16; ++kk) {
            float xv[4], wv[4];
            #pragma unroll
            for (int r = 0; r < 4; ++r) xv[r] = Xs[tr * 4 + r][kk];
            #pragma unroll
            for (int c = 0; c < 4; ++c) wv[c] = Ws[tc * 4 + c][kk];
            #pragma unroll
            for (int r = 0; r < 4; ++r)
                #pragma unroll
                for (int c = 0; c < 4; ++c)
                    acc[r][c] = fmaf(xv[r], wv[c], acc[r][c]);
        }
        __syncthreads();
    }
    #pragma unroll
    for (int r = 0; r < 4; ++r) {
        int n = n0 + tr * 4 + r;
        if (n < NN) {
            #pragma unroll
            for (int c = 0; c < 4; ++c)
                y[n * 128 + tc * 4 + c] = acc[r][c];
        }
    }
}

// ---------- layers 2/3 GEMM: y[n][0:32]=h@Wl.T, y[n][32:64]=h@Wr.T ----------
template<int K>
__global__ __launch_bounds__(256) void mm23_kernel(const float* __restrict__ h, const float* __restrict__ Wl,
                                                   const float* __restrict__ Wr, float* __restrict__ y) {
    __shared__ float Xs[32][K + 1];
    __shared__ float Ws[64][K + 1];
    const int t = threadIdx.x;
    const int n0 = blockIdx.x * 32;
    #pragma unroll
    for (int i = 0; i < (64 * K) / 256; ++i) {
        int e = t + i * 256;
        int row = e / K, col = e % K;
        Ws[row][col] = (row < 32) ? Wl[row * K + col] : Wr[(row - 32) * K + col];
    }
    #pragma unroll
    for (int i = 0; i < (32 * K) / 256; ++i) {
        int e = t + i * 256;
        int row = e / K, col = e % K;
        int n = n0 + row;
        Xs[row][col] = (n < NN) ? h[n * K + col] : 0.f;
    }
    __syncthreads();
    const int tr = t >> 5;  // rows tr*4..
    const int tc = t & 31;  // cols tc*2..
    float acc[4][2] = {};
    #pragma unroll 4
    for (int k = 0; k < K; ++k) {
        float xv[4], wv[2];
        #pragma unroll
        for (int r = 0; r < 4; ++r) xv[r] = Xs[tr * 4 + r][k];
        wv[0] = Ws[tc * 2][k];
        wv[1] = Ws[tc * 2 + 1][k];
        #pragma unroll
        for (int r = 0; r < 4; ++r) {
            acc[r][0] = fmaf(xv[r], wv[0], acc[r][0]);
            acc[r][1] = fmaf(xv[r], wv[1], acc[r][1]);
        }
    }
    #pragma unroll
    for (int r = 0; r < 4; ++r) {
        int n = n0 + tr * 4 + r;
        if (n < NN) {
            y[n * 64 + tc * 2]     = acc[r][0];
            y[n * 64 + tc * 2 + 1] = acc[r][1];
        }
    }
}

// ---------- edge scatter: agg[dst] += y_l[src] ----------
template<int DIM, int YSTRIDE>
__global__ __launch_bounds__(256) void agg_kernel(const float* __restrict__ y, const int* __restrict__ src,
                                                  const int* __restrict__ dst, float* __restrict__ agg) {
    int gid = blockIdx.x * 256 + threadIdx.x;
    int e = gid / DIM, d = gid % DIM;
    if (e >= NE) return;
    atomicAdd(&agg[dst[e] * DIM + d], y[src[e] * YSTRIDE + d]);
}

// ---------- h = relu(agg*deg_inv + b + y_r) ----------
template<int DIM, int YSTRIDE>
__global__ __launch_bounds__(256) void combine_kernel(const float* __restrict__ agg, const float* __restrict__ y,
                                                      const float* __restrict__ deg_inv, const float* __restrict__ b,
                                                      float* __restrict__ h) {
    int gid = blockIdx.x * 256 + threadIdx.x;
    if (gid >= NN * DIM) return;
    int n = gid / DIM, d = gid % DIM;
    float v = agg[gid] * deg_inv[n] + b[d] + y[n * YSTRIDE + DIM + d];
    h[gid] = fmaxf(v, 0.f);
}

// ---------- post_mp + log_softmax: one wave per node ----------
__global__ __launch_bounds__(256) void final_kernel(const float* __restrict__ h,
                                                    const float* __restrict__ M1w, const float* __restrict__ M1b,
                                                    const float* __restrict__ M2w, const float* __restrict__ M2b,
                                                    float* __restrict__ out) {
    int wv = (blockIdx.x * 256 + threadIdx.x) >> 6;
    int lane = threadIdx.x & 63;
    if (wv >= NN) return;  // uniform per wave
    float hv = (lane < 32) ? h[wv * 32 + lane] : 0.f;
    float tv = (lane < 32) ? M1b[lane] : 0.f;
    #pragma unroll 8
    for (int k = 0; k < 32; ++k) {
        float hk = __shfl(hv, k, 64);
        if (lane < 32) tv = fmaf(hk, M1w[lane * 32 + k], tv);
    }
    float uv = (lane < 7) ? M2b[lane] : 0.f;
    #pragma unroll 8
    for (int k = 0; k < 32; ++k) {
        float tk = __shfl(tv, k, 64);
        if (lane < 7) uv = fmaf(tk, M2w[lane * 32 + k], uv);
    }
    float m = -1e30f;
    float uc[7];
    #pragma unroll
    for (int c = 0; c < 7; ++c) { uc[c] = __shfl(uv, c, 64); m = fmaxf(m, uc[c]); }
    float s = 0.f;
    #pragma unroll
    for (int c = 0; c < 7; ++c) s += expf(uc[c] - m);
    float lse = m + logf(s);
    if (lane < 7) out[wv * 7 + lane] = uv - lse;
}

extern "C" void kernel_launch(void* const* d_in, const int* in_sizes, int n_in,
                              void* d_out, int out_size, void* d_ws, size_t ws_size,
                              hipStream_t stream) {
    const float* x   = (const float*)d_in[0];
    const int*   eix = (const int*)d_in[1];
    const float* W1l = (const float*)d_in[2];
    const float* b1  = (const float*)d_in[3];
    const float* W1r = (const float*)d_in[4];
    const float* W2l = (const float*)d_in[5];
    const float* b2  = (const float*)d_in[6];
    const float* W2r = (const float*)d_in[7];
    const float* W3l = (const float*)d_in[8];
    const float* b3  = (const float*)d_in[9];
    const float* W3r = (const float*)d_in[10];
    const float* M1w = (const float*)d_in[11];
    const float* M1b = (const float*)d_in[12];
    const float* M2w = (const float*)d_in[13];
    const float* M2b = (const float*)d_in[14];
    float* out = (float*)d_out;

    char* w = (char*)d_ws;
    int*   flag = (int*)w;    w += 256;
    int*   srcI = (int*)w;    w += NE * 4;
    int*   dstI = (int*)w;    w += NE * 4;
    float* deg  = (float*)w;  w += 40960;
    float* y    = (float*)w;  w += NN * 128 * 4;
    float* agg  = (float*)w;  w += NN * 64 * 4;
    float* h    = (float*)w;  w += NN * 64 * 4;

    detect_kernel<<<1, 256, 0, stream>>>(eix, flag);
    repack_kernel<<<(NE + 255) / 256, 256, 0, stream>>>(eix, flag, srcI, dstI);

    hipMemsetAsync(deg, 0, NN * 4, stream);
    deg_kernel<<<(NE + 255) / 256, 256, 0, stream>>>(dstI, deg);
    deginv_kernel<<<(NN + 255) / 256, 256, 0, stream>>>(deg);

    // layer 1
    mm1_kernel<<<(NN + 31) / 32, 256, 0, stream>>>(x, W1l, W1r, y);
    hipMemsetAsync(agg, 0, NN * 64 * 4, stream);
    agg_kernel<64, 128><<<(NE * 64) / 256, 256, 0, stream>>>(y, srcI, dstI, agg);
    combine_kernel<64, 128><<<(NN * 64 + 255) / 256, 256, 0, stream>>>(agg, y, deg, b1, h);

    // layer 2
    mm23_kernel<64><<<(NN + 31) / 32, 256, 0, stream>>>(h, W2l, W2r, y);
    hipMemsetAsync(agg, 0, NN * 32 * 4, stream);
    agg_kernel<32, 64><<<(NE * 32) / 256, 256, 0, stream>>>(y, srcI, dstI, agg);
    combine_kernel<32, 64><<<(NN * 32 + 255) / 256, 256, 0, stream>>>(agg, y, deg, b2, h);

    // layer 3
    mm23_kernel<32><<<(NN + 31) / 32, 256, 0, stream>>>(h, W3l, W3r, y);
    hipMemsetAsync(agg, 0, NN * 32 * 4, stream);
    agg_kernel<32, 64><<<(NE * 32) / 256, 256, 0, stream>>>(y, srcI, dstI, agg);
    combine_kernel<32, 64><<<(NN * 32 + 255) / 256, 256, 0, stream>>>(agg, y, deg, b3, h);

    // post_mp + log_softmax
    final_kernel<<<(NN + 3) / 4, 256, 0, stream>>>(h, M1w, M1b, M2w, M2b, out);
}

// Round 2
// 231.935 us; speedup vs baseline: 2.0245x; 2.0245x over previous
//
#include <hip/hip_runtime.h>

#define NN 10000
#define NE 160000
#define KD 1433
#define KP 1536   // padded K for bf16 GEMM (multiple of 384)

typedef unsigned short u16;
typedef __attribute__((ext_vector_type(4))) float f32x4;
typedef __attribute__((ext_vector_type(8))) short bf16x8;

__device__ __forceinline__ u16 f2bf(float f) {
    union { float f; unsigned u; } v; v.f = f;
    unsigned r = (v.u + 0x7FFF + ((v.u >> 16) & 1)) >> 16;
    return (u16)r;
}

// ---------- edge dtype detect + repack (int64 vs int32 robustness) ----------
__global__ __launch_bounds__(256) void detect_kernel(const int* __restrict__ e, int* __restrict__ flag) {
    __shared__ int nz;
    if (threadIdx.x == 0) nz = 0;
    __syncthreads();
    int cnt = 0;
    for (int i = threadIdx.x; i < 4000; i += 256)
        if (e[2 * i + 1] != 0) cnt++;
    if (cnt) atomicAdd(&nz, cnt);
    __syncthreads();
    if (threadIdx.x == 0) *flag = (nz == 0) ? 1 : 0;  // 1 => data is int64
}

__global__ __launch_bounds__(256) void repack_kernel(const int* __restrict__ e, const int* __restrict__ flag,
                                                     int* __restrict__ srcI, int* __restrict__ dstI) {
    int i = blockIdx.x * 256 + threadIdx.x;
    if (i >= NE) return;
    if (*flag) {  // int64 little-endian: take low words
        srcI[i] = e[2 * i];
        dstI[i] = e[2 * (NE + i)];
    } else {
        srcI[i] = e[i];
        dstI[i] = e[NE + i];
    }
}

// ---------- degree ----------
__global__ __launch_bounds__(256) void deg_kernel(const int* __restrict__ dst, float* __restrict__ deg) {
    int i = blockIdx.x * 256 + threadIdx.x;
    if (i < NE) atomicAdd(&deg[dst[i]], 1.0f);
}

__global__ __launch_bounds__(256) void deginv_kernel(float* __restrict__ deg) {
    int i = blockIdx.x * 256 + threadIdx.x;
    if (i < NN) deg[i] = (deg[i] > 0.f) ? (1.0f / deg[i]) : 0.f;
}

// ---------- fp32 -> bf16 conversion, K padded to KP ----------
__global__ __launch_bounds__(256) void convx_kernel(const float* __restrict__ x, u16* __restrict__ xb) {
    int gid = blockIdx.x * 256 + threadIdx.x;
    if (gid >= NN * (KP / 8)) return;
    int n = gid / (KP / 8), k0 = (gid % (KP / 8)) * 8;
    u16 u[8];
    #pragma unroll
    for (int i = 0; i < 8; ++i) {
        int k = k0 + i;
        u[i] = (k < KD) ? f2bf(x[n * KD + k]) : (u16)0;
    }
    *(uint4*)&xb[n * KP + k0] = *(const uint4*)u;
}

__global__ __launch_bounds__(256) void convw_kernel(const float* __restrict__ Wl, const float* __restrict__ Wr,
                                                    u16* __restrict__ Wb) {
    int gid = blockIdx.x * 256 + threadIdx.x;
    if (gid >= 128 * (KP / 8)) return;
    int r = gid / (KP / 8), k0 = (gid % (KP / 8)) * 8;
    const float* srcw = (r < 64) ? (Wl + r * KD) : (Wr + (r - 64) * KD);
    u16 u[8];
    #pragma unroll
    for (int i = 0; i < 8; ++i) {
        int k = k0 + i;
        u[i] = (k < KD) ? f2bf(srcw[k]) : (u16)0;
    }
    *(uint4*)&Wb[r * KP + k0] = *(const uint4*)u;
}

// ---------- layer-1 MFMA GEMM: y[n][0:64]=x@W1l.T, y[n][64:128]=x@W1r.T ----------
// grid (313, 4): 32 rows per block, split-K into 4 chunks of 384; atomicAdd partials.
__global__ __launch_bounds__(256) void mm1_mfma(const u16* __restrict__ xb, const u16* __restrict__ Wb,
                                                float* __restrict__ y) {
    __shared__ u16 XT[32 * 32];
    __shared__ u16 WT[128 * 32];
    const int t = threadIdx.x;
    const int wvid = t >> 6, lane = t & 63;
    const int n0 = blockIdx.x * 32;
    const int kc0 = blockIdx.y * 384;

    // x staging: thread t -> row t>>3, 4 bf16 at col (t&7)*4
    const int xr = t >> 3, xc = (t & 7) * 4;
    const int xg = xc >> 3, xh = (xc >> 2) & 1;
    const int xlds = xr * 32 + (((xg ^ ((xr >> 1) & 3)) << 3)) + xh * 4;
    const int xrow = (n0 + xr < NN) ? (n0 + xr) : (NN - 1);
    const u16* xp = xb + xrow * KP + kc0 + xc;

    // W staging: thread t -> row t>>1, granules (t&1)*2 + {0,1} (16 bf16 = 32B)
    const int wr = t >> 1, wg0 = (t & 1) * 2;
    const int wlds0 = wr * 32 + ((( wg0      ^ ((wr >> 1) & 3)) << 3));
    const int wlds1 = wr * 32 + ((((wg0 + 1) ^ ((wr >> 1) & 3)) << 3));
    const u16* wp = Wb + wr * KP + kc0 + wg0 * 8;

    // fragment read offsets (swizzled)
    const int ar = lane & 15, ag = lane >> 4;
    int a_off[2], b_off[2];
    #pragma unroll
    for (int m = 0; m < 2; ++m) {
        int row = m * 16 + ar;
        a_off[m] = row * 32 + ((ag ^ ((row >> 1) & 3)) << 3);
    }
    #pragma unroll
    for (int c = 0; c < 2; ++c) {
        int row = wvid * 32 + c * 16 + ar;
        b_off[c] = row * 32 + ((ag ^ ((row >> 1) & 3)) << 3);
    }

    f32x4 acc[2][2] = {};
    uint2 xv = *(const uint2*)xp;
    uint4 wv0 = *(const uint4*)wp;
    uint4 wv1 = *(const uint4*)(wp + 8);

    for (int ks = 0; ks < 12; ++ks) {
        __syncthreads();
        *(uint2*)&XT[xlds] = xv;
        *(uint4*)&WT[wlds0] = wv0;
        *(uint4*)&WT[wlds1] = wv1;
        __syncthreads();
        if (ks < 11) {
            xv  = *(const uint2*)(xp + (ks + 1) * 32);
            wv0 = *(const uint4*)(wp + (ks + 1) * 32);
            wv1 = *(const uint4*)(wp + (ks + 1) * 32 + 8);
        }
        bf16x8 af0 = *(const bf16x8*)&XT[a_off[0]];
        bf16x8 af1 = *(const bf16x8*)&XT[a_off[1]];
        bf16x8 bf0 = *(const bf16x8*)&WT[b_off[0]];
        bf16x8 bf1 = *(const bf16x8*)&WT[b_off[1]];
        acc[0][0] = __builtin_amdgcn_mfma_f32_16x16x32_bf16(af0, bf0, acc[0][0], 0, 0, 0);
        acc[0][1] = __builtin_amdgcn_mfma_f32_16x16x32_bf16(af0, bf1, acc[0][1], 0, 0, 0);
        acc[1][0] = __builtin_amdgcn_mfma_f32_16x16x32_bf16(af1, bf0, acc[1][0], 0, 0, 0);
        acc[1][1] = __builtin_amdgcn_mfma_f32_16x16x32_bf16(af1, bf1, acc[1][1], 0, 0, 0);
    }

    // C/D layout: col = lane&15, row = (lane>>4)*4 + j   [m89]
    #pragma unroll
    for (int m = 0; m < 2; ++m) {
        #pragma unroll
        for (int c = 0; c < 2; ++c) {
            #pragma unroll
            for (int j = 0; j < 4; ++j) {
                int n = n0 + m * 16 + (lane >> 4) * 4 + j;
                int col = wvid * 32 + c * 16 + (lane & 15);
                if (n < NN) atomicAdd(&y[n * 128 + col], acc[m][c][j]);
            }
        }
    }
}

// ---------- layers 2/3 GEMM: y[n][0:32]=h@Wl.T, y[n][32:64]=h@Wr.T ----------
template<int K>
__global__ __launch_bounds__(256) void mm23_kernel(const float* __restrict__ h, const float* __restrict__ Wl,
                                                   const float* __restrict__ Wr, float* __restrict__ y) {
    __shared__ float Xs[32][K + 1];
    __shared__ float Ws[64][K + 1];
    const int t = threadIdx.x;
    const int n0 = blockIdx.x * 32;
    #pragma unroll
    for (int i = 0; i < (64 * K) / 256; ++i) {
        int e = t + i * 256;
        int row = e / K, col = e % K;
        Ws[row][col] = (row < 32) ? Wl[row * K + col] : Wr[(row - 32) * K + col];
    }
    #pragma unroll
    for (int i = 0; i < (32 * K) / 256; ++i) {
        int e = t + i * 256;
        int row = e / K, col = e % K;
        int n = n0 + row;
        Xs[row][col] = (n < NN) ? h[n * K + col] : 0.f;
    }
    __syncthreads();
    const int tr = t >> 5;
    const int tc = t & 31;
    float acc[4][2] = {};
    #pragma unroll 4
    for (int k = 0; k < K; ++k) {
        float xv[4], wv[2];
        #pragma unroll
        for (int r = 0; r < 4; ++r) xv[r] = Xs[tr * 4 + r][k];
        wv[0] = Ws[tc * 2][k];
        wv[1] = Ws[tc * 2 + 1][k];
        #pragma unroll
        for (int r = 0; r < 4; ++r) {
            acc[r][0] = fmaf(xv[r], wv[0], acc[r][0]);
            acc[r][1] = fmaf(xv[r], wv[1], acc[r][1]);
        }
    }
    #pragma unroll
    for (int r = 0; r < 4; ++r) {
        int n = n0 + tr * 4 + r;
        if (n < NN) {
            y[n * 64 + tc * 2]     = acc[r][0];
            y[n * 64 + tc * 2 + 1] = acc[r][1];
        }
    }
}

// ---------- edge scatter: agg[dst] += y_l[src] ----------
template<int DIM, int YSTRIDE>
__global__ __launch_bounds__(256) void agg_kernel(const float* __restrict__ y, const int* __restrict__ src,
                                                  const int* __restrict__ dst, float* __restrict__ agg) {
    int gid = blockIdx.x * 256 + threadIdx.x;
    int e = gid / DIM, d = gid % DIM;
    if (e >= NE) return;
    atomicAdd(&agg[dst[e] * DIM + d], y[src[e] * YSTRIDE + d]);
}

// ---------- h = relu(agg*deg_inv + b + y_r) ----------
template<int DIM, int YSTRIDE>
__global__ __launch_bounds__(256) void combine_kernel(const float* __restrict__ agg, const float* __restrict__ y,
                                                      const float* __restrict__ deg_inv, const float* __restrict__ b,
                                                      float* __restrict__ h) {
    int gid = blockIdx.x * 256 + threadIdx.x;
    if (gid >= NN * DIM) return;
    int n = gid / DIM, d = gid % DIM;
    float v = agg[gid] * deg_inv[n] + b[d] + y[n * YSTRIDE + DIM + d];
    h[gid] = fmaxf(v, 0.f);
}

// ---------- post_mp + log_softmax: one wave per node ----------
__global__ __launch_bounds__(256) void final_kernel(const float* __restrict__ h,
                                                    const float* __restrict__ M1w, const float* __restrict__ M1b,
                                                    const float* __restrict__ M2w, const float* __restrict__ M2b,
                                                    float* __restrict__ out) {
    int wv = (blockIdx.x * 256 + threadIdx.x) >> 6;
    int lane = threadIdx.x & 63;
    if (wv >= NN) return;  // uniform per wave
    float hv = (lane < 32) ? h[wv * 32 + lane] : 0.f;
    float tv = (lane < 32) ? M1b[lane] : 0.f;
    #pragma unroll 8
    for (int k = 0; k < 32; ++k) {
        float hk = __shfl(hv, k, 64);
        if (lane < 32) tv = fmaf(hk, M1w[lane * 32 + k], tv);
    }
    float uv = (lane < 7) ? M2b[lane] : 0.f;
    #pragma unroll 8
    for (int k = 0; k < 32; ++k) {
        float tk = __shfl(tv, k, 64);
        if (lane < 7) uv = fmaf(tk, M2w[lane * 32 + k], uv);
    }
    float m = -1e30f;
    float uc[7];
    #pragma unroll
    for (int c = 0; c < 7; ++c) { uc[c] = __shfl(uv, c, 64); m = fmaxf(m, uc[c]); }
    float s = 0.f;
    #pragma unroll
    for (int c = 0; c < 7; ++c) s += expf(uc[c] - m);
    float lse = m + logf(s);
    if (lane < 7) out[wv * 7 + lane] = uv - lse;
}

extern "C" void kernel_launch(void* const* d_in, const int* in_sizes, int n_in,
                              void* d_out, int out_size, void* d_ws, size_t ws_size,
                              hipStream_t stream) {
    const float* x   = (const float*)d_in[0];
    const int*   eix = (const int*)d_in[1];
    const float* W1l = (const float*)d_in[2];
    const float* b1  = (const float*)d_in[3];
    const float* W1r = (const float*)d_in[4];
    const float* W2l = (const float*)d_in[5];
    const float* b2  = (const float*)d_in[6];
    const float* W2r = (const float*)d_in[7];
    const float* W3l = (const float*)d_in[8];
    const float* b3  = (const float*)d_in[9];
    const float* W3r = (const float*)d_in[10];
    const float* M1w = (const float*)d_in[11];
    const float* M1b = (const float*)d_in[12];
    const float* M2w = (const float*)d_in[13];
    const float* M2b = (const float*)d_in[14];
    float* out = (float*)d_out;

    char* w = (char*)d_ws;
    int*   flag = (int*)w;    w += 256;
    int*   srcI = (int*)w;    w += NE * 4;
    int*   dstI = (int*)w;    w += NE * 4;
    float* deg  = (float*)w;  w += 40960;
    float* y    = (float*)w;  w += NN * 128 * 4;
    float* agg  = (float*)w;  w += NN * 64 * 4;
    float* h    = (float*)w;  w += NN * 64 * 4;
    u16*   xb   = (u16*)w;    w += (size_t)NN * KP * 2;
    u16*   Wb   = (u16*)w;    w += 128 * KP * 2;

    detect_kernel<<<1, 256, 0, stream>>>(eix, flag);
    repack_kernel<<<(NE + 255) / 256, 256, 0, stream>>>(eix, flag, srcI, dstI);

    hipMemsetAsync(deg, 0, NN * 4, stream);
    deg_kernel<<<(NE + 255) / 256, 256, 0, stream>>>(dstI, deg);
    deginv_kernel<<<(NN + 255) / 256, 256, 0, stream>>>(deg);

    // bf16 conversions for layer-1 GEMM
    convx_kernel<<<(NN * (KP / 8) + 255) / 256, 256, 0, stream>>>(x, xb);
    convw_kernel<<<(128 * (KP / 8) + 255) / 256, 256, 0, stream>>>(W1l, W1r, Wb);

    // layer 1 (MFMA, split-K atomics into y)
    hipMemsetAsync(y, 0, NN * 128 * 4, stream);
    {
        dim3 grid((NN + 31) / 32, 4);
        mm1_mfma<<<grid, 256, 0, stream>>>(xb, Wb, y);
    }
    hipMemsetAsync(agg, 0, NN * 64 * 4, stream);
    agg_kernel<64, 128><<<(NE * 64) / 256, 256, 0, stream>>>(y, srcI, dstI, agg);
    combine_kernel<64, 128><<<(NN * 64 + 255) / 256, 256, 0, stream>>>(agg, y, deg, b1, h);

    // layer 2
    mm23_kernel<64><<<(NN + 31) / 32, 256, 0, stream>>>(h, W2l, W2r, y);
    hipMemsetAsync(agg, 0, NN * 32 * 4, stream);
    agg_kernel<32, 64><<<(NE * 32) / 256, 256, 0, stream>>>(y, srcI, dstI, agg);
    combine_kernel<32, 64><<<(NN * 32 + 255) / 256, 256, 0, stream>>>(agg, y, deg, b2, h);

    // layer 3
    mm23_kernel<32><<<(NN + 31) / 32, 256, 0, stream>>>(h, W3l, W3r, y);
    hipMemsetAsync(agg, 0, NN * 32 * 4, stream);
    agg_kernel<32, 64><<<(NE * 32) / 256, 256, 0, stream>>>(y, srcI, dstI, agg);
    combine_kernel<32, 64><<<(NN * 32 + 255) / 256, 256, 0, stream>>>(agg, y, deg, b3, h);

    // post_mp + log_softmax
    final_kernel<<<(NN + 3) / 4, 256, 0, stream>>>(h, M1w, M1b, M2w, M2b, out);
}

// Round 5
// 199.601 us; speedup vs baseline: 2.3525x; 1.1620x over previous
//
#include <hip/hip_runtime.h>

#define NN 10000
#define NE 160000
#define KD 1433
#define KP 1536   // padded K for bf16 GEMM (multiple of 384)

typedef unsigned short u16;
typedef __attribute__((ext_vector_type(4))) float f32x4;
typedef __attribute__((ext_vector_type(8))) short bf16x8;

__device__ __forceinline__ u16 f2bf(float f) {
    union { float f; unsigned u; } v; v.f = f;
    unsigned r = (v.u + 0x7FFF + ((v.u >> 16) & 1)) >> 16;
    return (u16)r;
}

// ---------- edge dtype detect ----------
__global__ __launch_bounds__(256) void detect_kernel(const int* __restrict__ e, int* __restrict__ flag) {
    __shared__ int nz;
    if (threadIdx.x == 0) nz = 0;
    __syncthreads();
    int cnt = 0;
    for (int i = threadIdx.x; i < 4000; i += 256)
        if (e[2 * i + 1] != 0) cnt++;
    if (cnt) atomicAdd(&nz, cnt);
    __syncthreads();
    if (threadIdx.x == 0) *flag = (nz == 0) ? 1 : 0;  // 1 => data is int64
}

// ---------- repack edges + degree count (fused) ----------
__global__ __launch_bounds__(256) void repackdeg_kernel(const int* __restrict__ e, const int* __restrict__ flag,
                                                        int* __restrict__ srcI, int* __restrict__ dstI,
                                                        float* __restrict__ deg) {
    int i = blockIdx.x * 256 + threadIdx.x;
    if (i >= NE) return;
    int s, d;
    if (*flag) {  // int64 little-endian: take low words
        s = e[2 * i];
        d = e[2 * (NE + i)];
    } else {
        s = e[i];
        d = e[NE + i];
    }
    srcI[i] = s;
    dstI[i] = d;
    atomicAdd(&deg[d], 1.0f);
}

__global__ __launch_bounds__(256) void deginv_kernel(float* __restrict__ deg) {
    int i = blockIdx.x * 256 + threadIdx.x;
    if (i < NN) deg[i] = (deg[i] > 0.f) ? (1.0f / deg[i]) : 0.f;
}

// ---------- W1 -> bf16 (tiny: 128x1536) ----------
__global__ __launch_bounds__(256) void convw_kernel(const float* __restrict__ Wl, const float* __restrict__ Wr,
                                                    u16* __restrict__ Wb) {
    int gid = blockIdx.x * 256 + threadIdx.x;
    if (gid >= 128 * (KP / 8)) return;
    int r = gid / (KP / 8), k0 = (gid % (KP / 8)) * 8;
    const float* srcw = (r < 64) ? (Wl + r * KD) : (Wr + (r - 64) * KD);
    u16 u[8];
    #pragma unroll
    for (int i = 0; i < 8; ++i) {
        int k = k0 + i;
        u[i] = (k < KD) ? f2bf(srcw[k]) : (u16)0;
    }
    *(uint4*)&Wb[r * KP + k0] = *(const uint4*)u;
}

// ---------- layer-1 MFMA GEMM with fused fp32->bf16 x staging ----------
// y[n][0:64]=x@W1l.T, y[n][64:128]=x@W1r.T
// grid (313, 4): 32 rows per block, split-K chunks of 384; atomicAdd partials into y.
__global__ __launch_bounds__(256) void mm1_mfma(const float* __restrict__ x, const u16* __restrict__ Wb,
                                                float* __restrict__ y) {
    __shared__ u16 XT[32 * 32];
    __shared__ u16 WT[128 * 32];
    const int t = threadIdx.x;
    const int wvid = t >> 6, lane = t & 63;
    const int n0 = blockIdx.x * 32;
    const int kc0 = blockIdx.y * 384;

    // x staging: thread t -> row t>>3, 4 fp32 at col (t&7)*4, convert to bf16
    const int xr = t >> 3, xc = (t & 7) * 4;
    const int xg = xc >> 3, xh = (xc >> 2) & 1;
    const int xlds = xr * 32 + ((xg ^ ((xr >> 1) & 3)) << 3) + xh * 4;
    const int xrow = (n0 + xr < NN) ? (n0 + xr) : (NN - 1);
    const float* xp = x + (size_t)xrow * KD;
    const int kb = kc0 + xc;

    // W staging: thread t -> row t>>1, granules (t&1)*2 + {0,1}
    const int wr = t >> 1, wg0 = (t & 1) * 2;
    const int wlds0 = wr * 32 + ((( wg0      ^ ((wr >> 1) & 3)) << 3));
    const int wlds1 = wr * 32 + ((((wg0 + 1) ^ ((wr >> 1) & 3)) << 3));
    const u16* wp = Wb + wr * KP + kc0 + wg0 * 8;

    // fragment read offsets (swizzled)
    const int ar = lane & 15, ag = lane >> 4;
    int a_off[2], b_off[2];
    #pragma unroll
    for (int m = 0; m < 2; ++m) {
        int row = m * 16 + ar;
        a_off[m] = row * 32 + ((ag ^ ((row >> 1) & 3)) << 3);
    }
    #pragma unroll
    for (int c = 0; c < 2; ++c) {
        int row = wvid * 32 + c * 16 + ar;
        b_off[c] = row * 32 + ((ag ^ ((row >> 1) & 3)) << 3);
    }

    f32x4 acc[2][2] = {};

    float xf[4];
    #pragma unroll
    for (int i = 0; i < 4; ++i) {
        int k = kb + i;
        float v = xp[k < KD ? k : KD - 1];
        xf[i] = (k < KD) ? v : 0.f;
    }
    uint4 wv0 = *(const uint4*)wp;
    uint4 wv1 = *(const uint4*)(wp + 8);

    for (int ks = 0; ks < 12; ++ks) {
        uint2 xv;
        u16* xu = (u16*)&xv;
        #pragma unroll
        for (int i = 0; i < 4; ++i) xu[i] = f2bf(xf[i]);
        __syncthreads();
        *(uint2*)&XT[xlds] = xv;
        *(uint4*)&WT[wlds0] = wv0;
        *(uint4*)&WT[wlds1] = wv1;
        __syncthreads();
        if (ks < 11) {
            #pragma unroll
            for (int i = 0; i < 4; ++i) {
                int k = kb + (ks + 1) * 32 + i;
                float v = xp[k < KD ? k : KD - 1];
                xf[i] = (k < KD) ? v : 0.f;
            }
            wv0 = *(const uint4*)(wp + (ks + 1) * 32);
            wv1 = *(const uint4*)(wp + (ks + 1) * 32 + 8);
        }
        bf16x8 af0 = *(const bf16x8*)&XT[a_off[0]];
        bf16x8 af1 = *(const bf16x8*)&XT[a_off[1]];
        bf16x8 bfr0 = *(const bf16x8*)&WT[b_off[0]];
        bf16x8 bfr1 = *(const bf16x8*)&WT[b_off[1]];
        acc[0][0] = __builtin_amdgcn_mfma_f32_16x16x32_bf16(af0, bfr0, acc[0][0], 0, 0, 0);
        acc[0][1] = __builtin_amdgcn_mfma_f32_16x16x32_bf16(af0, bfr1, acc[0][1], 0, 0, 0);
        acc[1][0] = __builtin_amdgcn_mfma_f32_16x16x32_bf16(af1, bfr0, acc[1][0], 0, 0, 0);
        acc[1][1] = __builtin_amdgcn_mfma_f32_16x16x32_bf16(af1, bfr1, acc[1][1], 0, 0, 0);
    }

    // C/D layout: col = lane&15, row = (lane>>4)*4 + j   [m89]
    #pragma unroll
    for (int m = 0; m < 2; ++m) {
        #pragma unroll
        for (int c = 0; c < 2; ++c) {
            #pragma unroll
            for (int j = 0; j < 4; ++j) {
                int n = n0 + m * 16 + (lane >> 4) * 4 + j;
                int col = wvid * 32 + c * 16 + (lane & 15);
                if (n < NN) atomicAdd(&y[n * 128 + col], acc[m][c][j]);
            }
        }
    }
}

// ---------- layers 2/3 GEMM: y[n][0:32]=h@Wl.T, y[n][32:64]=h@Wr.T ----------
template<int K>
__global__ __launch_bounds__(256) void mm23_kernel(const float* __restrict__ h, const float* __restrict__ Wl,
                                                   const float* __restrict__ Wr, float* __restrict__ y) {
    __shared__ float Xs[32][K + 1];
    __shared__ float Ws[64][K + 1];
    const int t = threadIdx.x;
    const int n0 = blockIdx.x * 32;
    #pragma unroll
    for (int i = 0; i < (64 * K) / 256; ++i) {
        int e = t + i * 256;
        int row = e / K, col = e % K;
        Ws[row][col] = (row < 32) ? Wl[row * K + col] : Wr[(row - 32) * K + col];
    }
    #pragma unroll
    for (int i = 0; i < (32 * K) / 256; ++i) {
        int e = t + i * 256;
        int row = e / K, col = e % K;
        int n = n0 + row;
        Xs[row][col] = (n < NN) ? h[n * K + col] : 0.f;
    }
    __syncthreads();
    const int tr = t >> 5;
    const int tc = t & 31;
    float acc[4][2] = {};
    #pragma unroll 4
    for (int k = 0; k < K; ++k) {
        float xv[4], wv[2];
        #pragma unroll
        for (int r = 0; r < 4; ++r) xv[r] = Xs[tr * 4 + r][k];
        wv[0] = Ws[tc * 2][k];
        wv[1] = Ws[tc * 2 + 1][k];
        #pragma unroll
        for (int r = 0; r < 4; ++r) {
            acc[r][0] = fmaf(xv[r], wv[0], acc[r][0]);
            acc[r][1] = fmaf(xv[r], wv[1], acc[r][1]);
        }
    }
    #pragma unroll
    for (int r = 0; r < 4; ++r) {
        int n = n0 + tr * 4 + r;
        if (n < NN) {
            y[n * 64 + tc * 2]     = acc[r][0];
            y[n * 64 + tc * 2 + 1] = acc[r][1];
        }
    }
}

// ---------- edge scatter: agg[dst] += y_l[src] ----------
template<int DIM, int YSTRIDE>
__global__ __launch_bounds__(256) void agg_kernel(const float* __restrict__ y, const int* __restrict__ src,
                                                  const int* __restrict__ dst, float* __restrict__ agg) {
    int gid = blockIdx.x * 256 + threadIdx.x;
    int e = gid / DIM, d = gid % DIM;
    if (e >= NE) return;
    atomicAdd(&agg[dst[e] * DIM + d], y[src[e] * YSTRIDE + d]);
}

// ---------- h = relu(agg*deg_inv + b + y_r) ----------
template<int DIM, int YSTRIDE>
__global__ __launch_bounds__(256) void combine_kernel(const float* __restrict__ agg, const float* __restrict__ y,
                                                      const float* __restrict__ deg_inv, const float* __restrict__ b,
                                                      float* __restrict__ h) {
    int gid = blockIdx.x * 256 + threadIdx.x;
    if (gid >= NN * DIM) return;
    int n = gid / DIM, d = gid % DIM;
    float v = agg[gid] * deg_inv[n] + b[d] + y[n * YSTRIDE + DIM + d];
    h[gid] = fmaxf(v, 0.f);
}

// ---------- post_mp + log_softmax: one wave per node ----------
__global__ __launch_bounds__(256) void final_kernel(const float* __restrict__ h,
                                                    const float* __restrict__ M1w, const float* __restrict__ M1b,
                                                    const float* __restrict__ M2w, const float* __restrict__ M2b,
                                                    float* __restrict__ out) {
    int wv = (blockIdx.x * 256 + threadIdx.x) >> 6;
    int lane = threadIdx.x & 63;
    if (wv >= NN) return;  // uniform per wave
    float hv = (lane < 32) ? h[wv * 32 + lane] : 0.f;
    float tv = (lane < 32) ? M1b[lane] : 0.f;
    #pragma unroll 8
    for (int k = 0; k < 32; ++k) {
        float hk = __shfl(hv, k, 64);
        if (lane < 32) tv = fmaf(hk, M1w[lane * 32 + k], tv);
    }
    float uv = (lane < 7) ? M2b[lane] : 0.f;
    #pragma unroll 8
    for (int k = 0; k < 32; ++k) {
        float tk = __shfl(tv, k, 64);
        if (lane < 7) uv = fmaf(tk, M2w[lane * 32 + k], uv);
    }
    float m = -1e30f;
    float uc[7];
    #pragma unroll
    for (int c = 0; c < 7; ++c) { uc[c] = __shfl(uv, c, 64); m = fmaxf(m, uc[c]); }
    float s = 0.f;
    #pragma unroll
    for (int c = 0; c < 7; ++c) s += expf(uc[c] - m);
    float lse = m + logf(s);
    if (lane < 7) out[wv * 7 + lane] = uv - lse;
}

extern "C" void kernel_launch(void* const* d_in, const int* in_sizes, int n_in,
                              void* d_out, int out_size, void* d_ws, size_t ws_size,
                              hipStream_t stream) {
    const float* x   = (const float*)d_in[0];
    const int*   eix = (const int*)d_in[1];
    const float* W1l = (const float*)d_in[2];
    const float* b1  = (const float*)d_in[3];
    const float* W1r = (const float*)d_in[4];
    const float* W2l = (const float*)d_in[5];
    const float* b2  = (const float*)d_in[6];
    const float* W2r = (const float*)d_in[7];
    const float* W3l = (const float*)d_in[8];
    const float* b3  = (const float*)d_in[9];
    const float* W3r = (const float*)d_in[10];
    const float* M1w = (const float*)d_in[11];
    const float* M1b = (const float*)d_in[12];
    const float* M2w = (const float*)d_in[13];
    const float* M2b = (const float*)d_in[14];
    float* out = (float*)d_out;

    char* w = (char*)d_ws;
    int*   flag = (int*)w;    w += 256;
    int*   srcI = (int*)w;    w += NE * 4;
    int*   dstI = (int*)w;    w += NE * 4;
    float* deg  = (float*)w;  w += 40960;
    float* y    = (float*)w;  w += NN * 128 * 4;
    float* agg  = (float*)w;  w += NN * 64 * 4;
    float* h    = (float*)w;  w += NN * 64 * 4;
    u16*   Wb   = (u16*)w;    w += 128 * KP * 2;

    detect_kernel<<<1, 256, 0, stream>>>(eix, flag);
    hipMemsetAsync(deg, 0, NN * 4, stream);
    repackdeg_kernel<<<(NE + 255) / 256, 256, 0, stream>>>(eix, flag, srcI, dstI, deg);
    deginv_kernel<<<(NN + 255) / 256, 256, 0, stream>>>(deg);

    convw_kernel<<<(128 * (KP / 8) + 255) / 256, 256, 0, stream>>>(W1l, W1r, Wb);

    // layer 1 (MFMA, fused fp32->bf16 staging, split-K atomics into y)
    hipMemsetAsync(y, 0, NN * 128 * 4, stream);
    {
        dim3 grid((NN + 31) / 32, 4);
        mm1_mfma<<<grid, 256, 0, stream>>>(x, Wb, y);
    }
    hipMemsetAsync(agg, 0, NN * 64 * 4, stream);
    agg_kernel<64, 128><<<(NE * 64) / 256, 256, 0, stream>>>(y, srcI, dstI, agg);
    combine_kernel<64, 128><<<(NN * 64 + 255) / 256, 256, 0, stream>>>(agg, y, deg, b1, h);

    // layer 2
    mm23_kernel<64><<<(NN + 31) / 32, 256, 0, stream>>>(h, W2l, W2r, y);
    hipMemsetAsync(agg, 0, NN * 32 * 4, stream);
    agg_kernel<32, 64><<<(NE * 32) / 256, 256, 0, stream>>>(y, srcI, dstI, agg);
    combine_kernel<32, 64><<<(NN * 32 + 255) / 256, 256, 0, stream>>>(agg, y, deg, b2, h);

    // layer 3
    mm23_kernel<32><<<(NN + 31) / 32, 256, 0, stream>>>(h, W3l, W3r, y);
    hipMemsetAsync(agg, 0, NN * 32 * 4, stream);
    agg_kernel<32, 64><<<(NE * 32) / 256, 256, 0, stream>>>(y, srcI, dstI, agg);
    combine_kernel<32, 64><<<(NN * 32 + 255) / 256, 256, 0, stream>>>(agg, y, deg, b3, h);

    // post_mp + log_softmax
    final_kernel<<<(NN + 3) / 4, 256, 0, stream>>>(h, M1w, M1b, M2w, M2b, out);
}

// Round 7
// 194.082 us; speedup vs baseline: 2.4194x; 1.0284x over previous
//
#include <hip/hip_runtime.h>

#define NN 10000
#define NE 160000
#define KD 1433
#define KP 1536    // padded K (zero-filled in Wb; x tail handled in-kernel)
#define SK 8       // split-K factor for mm1
#define CHUNK 192  // KP/SK
#define ITERS 6    // CHUNK/32

typedef unsigned short u16;
typedef __attribute__((ext_vector_type(4))) float f32x4;
typedef __attribute__((ext_vector_type(8))) short bf16x8;
typedef __attribute__((ext_vector_type(4), aligned(4))) float f32x4u;  // 4B-aligned vector load

__device__ __forceinline__ u16 f2bf(float f) {
    union { float f; unsigned u; } v; v.f = f;
    unsigned r = (v.u + 0x7FFF + ((v.u >> 16) & 1)) >> 16;
    return (u16)r;
}

// ---------- edge dtype detect ----------
__global__ __launch_bounds__(256) void detect_kernel(const int* __restrict__ e, int* __restrict__ flag) {
    __shared__ int nz;
    if (threadIdx.x == 0) nz = 0;
    __syncthreads();
    int cnt = 0;
    for (int i = threadIdx.x; i < 4000; i += 256)
        if (e[2 * i + 1] != 0) cnt++;
    if (cnt) atomicAdd(&nz, cnt);
    __syncthreads();
    if (threadIdx.x == 0) *flag = (nz == 0) ? 1 : 0;  // 1 => data is int64
}

// ---------- repack edges + degree count (fused) ----------
__global__ __launch_bounds__(256) void repackdeg_kernel(const int* __restrict__ e, const int* __restrict__ flag,
                                                        int* __restrict__ srcI, int* __restrict__ dstI,
                                                        float* __restrict__ deg) {
    int i = blockIdx.x * 256 + threadIdx.x;
    if (i >= NE) return;
    int s, d;
    if (*flag) {
        s = e[2 * i];
        d = e[2 * (NE + i)];
    } else {
        s = e[i];
        d = e[NE + i];
    }
    srcI[i] = s;
    dstI[i] = d;
    atomicAdd(&deg[d], 1.0f);
}

__global__ __launch_bounds__(256) void deginv_kernel(float* __restrict__ deg) {
    int i = blockIdx.x * 256 + threadIdx.x;
    if (i < NN) deg[i] = (deg[i] > 0.f) ? (1.0f / deg[i]) : 0.f;
}

// ---------- W1 -> bf16 (128 x KP, zero-padded) ----------
__global__ __launch_bounds__(256) void convw_kernel(const float* __restrict__ Wl, const float* __restrict__ Wr,
                                                    u16* __restrict__ Wb) {
    int gid = blockIdx.x * 256 + threadIdx.x;
    if (gid >= 128 * (KP / 8)) return;
    int r = gid / (KP / 8), k0 = (gid % (KP / 8)) * 8;
    const float* srcw = (r < 64) ? (Wl + r * KD) : (Wr + (r - 64) * KD);
    u16 u[8];
    #pragma unroll
    for (int i = 0; i < 8; ++i) {
        int k = k0 + i;
        u[i] = (k < KD) ? f2bf(srcw[k]) : (u16)0;
    }
    *(uint4*)&Wb[r * KP + k0] = *(const uint4*)u;
}

// ---------- layer-1 MFMA GEMM: A-frags direct from global, W double-buffered in LDS ----------
// y[n][0:64]=x@W1l.T, y[n][64:128]=x@W1r.T ; grid (157, SK), atomicAdd partials.
__device__ __forceinline__ void load8(const float* __restrict__ xp, int kk, float4& a, float4& b) {
    if (kk + 7 < KD) {
        f32x4u v0 = *(const f32x4u*)(xp + kk);
        f32x4u v1 = *(const f32x4u*)(xp + kk + 4);
        a = make_float4(v0.x, v0.y, v0.z, v0.w);
        b = make_float4(v1.x, v1.y, v1.z, v1.w);
    } else {
        float t[8];
        #pragma unroll
        for (int i = 0; i < 8; ++i) t[i] = (kk + i < KD) ? xp[kk + i] : 0.f;
        a = make_float4(t[0], t[1], t[2], t[3]);
        b = make_float4(t[4], t[5], t[6], t[7]);
    }
}

__global__ __launch_bounds__(256) void mm1_mfma(const float* __restrict__ x, const u16* __restrict__ Wb,
                                                float* __restrict__ y) {
    __shared__ u16 WT[2][128 * 40];  // stride 40 elems (80B): 16B-aligned rows, 2-way banks (free)
    const int t = threadIdx.x;
    const int w = t >> 6, lane = t & 63;
    const int n0 = blockIdx.x * 64;
    const int kc0 = blockIdx.y * CHUNK;

    // A addressing: lane holds A[row=lane&15][k=(lane>>4)*8 + j]
    const int arow = lane & 15, ag = lane >> 4;
    int nrow = n0 + w * 16 + arow;
    if (nrow >= NN) nrow = NN - 1;
    const float* xp = x + (size_t)nrow * KD;

    // W staging: thread t -> W row t>>1 (= output col), 16 bf16 at k-offset (t&1)*16
    const int wr = t >> 1, wh = t & 1;
    const u16* wp = Wb + wr * KP + kc0 + wh * 16;
    const int wlds = wr * 40 + wh * 16;

    f32x4 acc[8] = {};  // frag f -> output cols f*16 .. f*16+15

    // prologue: W(0) -> buf0, A(0) -> regs
    uint4 wv0 = *(const uint4*)wp;
    uint4 wv1 = *(const uint4*)(wp + 8);
    float4 a0, a1;
    load8(xp, kc0 + ag * 8, a0, a1);
    *(uint4*)&WT[0][wlds] = wv0;
    *(uint4*)&WT[0][wlds + 8] = wv1;

    for (int ks = 0; ks < ITERS; ++ks) {
        const bool more = (ks + 1 < ITERS);
        uint4 nwv0, nwv1;
        if (more) {
            nwv0 = *(const uint4*)(wp + (ks + 1) * 32);
            nwv1 = *(const uint4*)(wp + (ks + 1) * 32 + 8);
        }
        __syncthreads();  // WT[ks&1] complete; everyone done with WT[(ks+1)&1]
        // convert current A to bf16 fragment
        bf16x8 af;
        {
            u16 au[8];
            au[0] = f2bf(a0.x); au[1] = f2bf(a0.y); au[2] = f2bf(a0.z); au[3] = f2bf(a0.w);
            au[4] = f2bf(a1.x); au[5] = f2bf(a1.y); au[6] = f2bf(a1.z); au[7] = f2bf(a1.w);
            af = *(const bf16x8*)au;
        }
        float4 na0, na1;
        if (more) load8(xp, kc0 + (ks + 1) * 32 + ag * 8, na0, na1);
        const u16* wtb = &WT[ks & 1][0];
        #pragma unroll
        for (int f = 0; f < 8; ++f) {
            bf16x8 bfr = *(const bf16x8*)&wtb[(f * 16 + arow) * 40 + ag * 8];
            acc[f] = __builtin_amdgcn_mfma_f32_16x16x32_bf16(af, bfr, acc[f], 0, 0, 0);
        }
        if (more) {
            u16* wdst = &WT[(ks + 1) & 1][wlds];
            *(uint4*)wdst = nwv0;
            *(uint4*)(wdst + 8) = nwv1;
            a0 = na0; a1 = na1;
        }
    }

    // C/D layout: col = lane&15, row = (lane>>4)*4 + j
    #pragma unroll
    for (int f = 0; f < 8; ++f) {
        #pragma unroll
        for (int j = 0; j < 4; ++j) {
            int n = n0 + w * 16 + ag * 4 + j;
            int col = f * 16 + arow;
            if (n < NN) atomicAdd(&y[n * 128 + col], acc[f][j]);
        }
    }
}

// ---------- fused combine + GEMM for layers 2/3 ----------
// h = relu(agg*deg_inv + b + yprev_right); yout[n][0:32]=h@Wl.T, [32:64]=h@Wr.T
template<int DIN>
__global__ __launch_bounds__(256) void mm23_fused(const float* __restrict__ agg, const float* __restrict__ yprev,
                                                  const float* __restrict__ deg_inv, const float* __restrict__ b,
                                                  const float* __restrict__ Wl, const float* __restrict__ Wr,
                                                  float* __restrict__ yout) {
    __shared__ float Xs[32][DIN + 1];
    __shared__ float Ws[64][DIN + 1];
    const int t = threadIdx.x;
    const int n0 = blockIdx.x * 32;
    #pragma unroll
    for (int i = 0; i < (64 * DIN) / 256; ++i) {
        int e = t + i * 256;
        int row = e / DIN, col = e % DIN;
        Ws[row][col] = (row < 32) ? Wl[row * DIN + col] : Wr[(row - 32) * DIN + col];
    }
    #pragma unroll
    for (int i = 0; i < (32 * DIN) / 256; ++i) {
        int e = t + i * 256;
        int r = e / DIN, d = e % DIN;
        int n = n0 + r;
        float v = 0.f;
        if (n < NN)
            v = fmaxf(agg[n * DIN + d] * deg_inv[n] + b[d] + yprev[n * 2 * DIN + DIN + d], 0.f);
        Xs[r][d] = v;
    }
    __syncthreads();
    const int tr = t >> 5;   // 4 rows
    const int tc = t & 31;   // 2 cols
    float acc[4][2] = {};
    #pragma unroll 4
    for (int k = 0; k < DIN; ++k) {
        float xv[4], wv[2];
        #pragma unroll
        for (int r = 0; r < 4; ++r) xv[r] = Xs[tr * 4 + r][k];
        wv[0] = Ws[tc * 2][k];
        wv[1] = Ws[tc * 2 + 1][k];
        #pragma unroll
        for (int r = 0; r < 4; ++r) {
            acc[r][0] = fmaf(xv[r], wv[0], acc[r][0]);
            acc[r][1] = fmaf(xv[r], wv[1], acc[r][1]);
        }
    }
    #pragma unroll
    for (int r = 0; r < 4; ++r) {
        int n = n0 + tr * 4 + r;
        if (n < NN) {
            yout[n * 64 + tc * 2]     = acc[r][0];
            yout[n * 64 + tc * 2 + 1] = acc[r][1];
        }
    }
}

// ---------- edge scatter: agg[dst] += y_l[src] ----------
template<int DIM, int YSTRIDE>
__global__ __launch_bounds__(256) void agg_kernel(const float* __restrict__ y, const int* __restrict__ src,
                                                  const int* __restrict__ dst, float* __restrict__ agg) {
    int gid = blockIdx.x * 256 + threadIdx.x;
    int e = gid / DIM, d = gid % DIM;
    if (e >= NE) return;
    atomicAdd(&agg[dst[e] * DIM + d], y[src[e] * YSTRIDE + d]);
}

// ---------- fused combine3 + post_mp + log_softmax: one wave per node ----------
__global__ __launch_bounds__(256) void final_fused(const float* __restrict__ agg, const float* __restrict__ y3,
                                                   const float* __restrict__ deg_inv, const float* __restrict__ b3,
                                                   const float* __restrict__ M1w, const float* __restrict__ M1b,
                                                   const float* __restrict__ M2w, const float* __restrict__ M2b,
                                                   float* __restrict__ out) {
    int wv = (blockIdx.x * 256 + threadIdx.x) >> 6;
    int lane = threadIdx.x & 63;
    if (wv >= NN) return;  // uniform per wave
    float hv = 0.f;
    if (lane < 32)
        hv = fmaxf(agg[wv * 32 + lane] * deg_inv[wv] + b3[lane] + y3[wv * 64 + 32 + lane], 0.f);
    float tv = (lane < 32) ? M1b[lane] : 0.f;
    #pragma unroll 8
    for (int k = 0; k < 32; ++k) {
        float hk = __shfl(hv, k, 64);
        if (lane < 32) tv = fmaf(hk, M1w[lane * 32 + k], tv);
    }
    float uv = (lane < 7) ? M2b[lane] : 0.f;
    #pragma unroll 8
    for (int k = 0; k < 32; ++k) {
        float tk = __shfl(tv, k, 64);
        if (lane < 7) uv = fmaf(tk, M2w[lane * 32 + k], uv);
    }
    float m = -1e30f;
    float uc[7];
    #pragma unroll
    for (int c = 0; c < 7; ++c) { uc[c] = __shfl(uv, c, 64); m = fmaxf(m, uc[c]); }
    float s = 0.f;
    #pragma unroll
    for (int c = 0; c < 7; ++c) s += expf(uc[c] - m);
    float lse = m + logf(s);
    if (lane < 7) out[wv * 7 + lane] = uv - lse;
}

extern "C" void kernel_launch(void* const* d_in, const int* in_sizes, int n_in,
                              void* d_out, int out_size, void* d_ws, size_t ws_size,
                              hipStream_t stream) {
    const float* x   = (const float*)d_in[0];
    const int*   eix = (const int*)d_in[1];
    const float* W1l = (const float*)d_in[2];
    const float* b1  = (const float*)d_in[3];
    const float* W1r = (const float*)d_in[4];
    const float* W2l = (const float*)d_in[5];
    const float* b2  = (const float*)d_in[6];
    const float* W2r = (const float*)d_in[7];
    const float* W3l = (const float*)d_in[8];
    const float* b3  = (const float*)d_in[9];
    const float* W3r = (const float*)d_in[10];
    const float* M1w = (const float*)d_in[11];
    const float* M1b = (const float*)d_in[12];
    const float* M2w = (const float*)d_in[13];
    const float* M2b = (const float*)d_in[14];
    float* out = (float*)d_out;

    char* w = (char*)d_ws;
    int*   flag = (int*)w;    w += 256;
    int*   srcI = (int*)w;    w += NE * 4;
    int*   dstI = (int*)w;    w += NE * 4;
    float* deg  = (float*)w;  w += 40960;
    // zero block: y | agg1 | agg2 | agg3 (one memset)
    float* y    = (float*)w;  w += NN * 128 * 4;
    float* agg1 = (float*)w;  w += NN * 64 * 4;
    float* agg2 = (float*)w;  w += NN * 32 * 4;
    float* agg3 = (float*)w;  w += NN * 32 * 4;
    float* y2   = (float*)w;  w += NN * 64 * 4;
    float* y3   = (float*)w;  w += NN * 64 * 4;
    u16*   Wb   = (u16*)w;    w += 128 * KP * 2;

    detect_kernel<<<1, 256, 0, stream>>>(eix, flag);
    hipMemsetAsync(deg, 0, NN * 4, stream);
    repackdeg_kernel<<<(NE + 255) / 256, 256, 0, stream>>>(eix, flag, srcI, dstI, deg);
    deginv_kernel<<<(NN + 255) / 256, 256, 0, stream>>>(deg);

    convw_kernel<<<(128 * (KP / 8) + 255) / 256, 256, 0, stream>>>(W1l, W1r, Wb);

    hipMemsetAsync(y, 0, (size_t)NN * 256 * 4, stream);  // y + agg1 + agg2 + agg3

    // layer 1
    {
        dim3 grid((NN + 63) / 64, SK);
        mm1_mfma<<<grid, 256, 0, stream>>>(x, Wb, y);
    }
    agg_kernel<64, 128><<<(NE * 64) / 256, 256, 0, stream>>>(y, srcI, dstI, agg1);

    // layer 2 (combine fused into GEMM staging)
    mm23_fused<64><<<(NN + 31) / 32, 256, 0, stream>>>(agg1, y, deg, b1, W2l, W2r, y2);
    agg_kernel<32, 64><<<(NE * 32) / 256, 256, 0, stream>>>(y2, srcI, dstI, agg2);

    // layer 3
    mm23_fused<32><<<(NN + 31) / 32, 256, 0, stream>>>(agg2, y2, deg, b2, W3l, W3r, y3);
    agg_kernel<32, 64><<<(NE * 32) / 256, 256, 0, stream>>>(y3, srcI, dstI, agg3);

    // combine3 + post_mp + log_softmax
    final_fused<<<(NN + 3) / 4, 256, 0, stream>>>(agg3, y3, deg, b3, M1w, M1b, M2w, M2b, out);
}